// Round 10
// baseline (75.932 us; speedup 1.0000x reference)
//
#include <hip/hip_runtime.h>
#include <math.h>

constexpr int N     = 8192;
constexpr int K     = 30;
constexpr int TPB   = 1024;               // pair kernel block size (16 waves)
constexpr int IPT   = 4;                  // i-rows per thread
constexpr int NIC   = N / (TPB * IPT);    // 2 i-chunks of 4096
constexpr int NJ    = 128;                // j-slices
constexpr int JSPAN = N / NJ;             // 64 j per block
constexpr int NBLK  = NIC * NJ;           // 256 blocks -> 1 per CU
constexpr int MTPB  = 256;                // mrl/final block size

// d_ws layout:
//   [0, 32768)        float   mrl[N]
//   [32768, 34816)    double  pnum[NBLK]
//   [34816, 35840)    int     pcnt[NBLK]

__global__ void mrl_kernel(const float* __restrict__ est,
                           const float* __restrict__ intervals,
                           float* __restrict__ mrl) {
    __shared__ float s_est[MTPB * K];     // this block's 256 rows, 30 KB

    const int tid  = threadIdx.x;
    const int row0 = blockIdx.x * MTPB;

    // coalesced staging: 256x30 floats = 3840 float2, 15 per thread
    const float2* src = (const float2*)(est + (size_t)row0 * K);
    float2* dst = (float2*)s_est;
#pragma unroll
    for (int t = 0; t < (MTPB * K) / (2 * MTPB); ++t)   // 15
        dst[t * MTPB + tid] = src[t * MTPB + tid];
    __syncthreads();

    const float* e = s_est + tid * K;
    double sp = 1.0, m = 0.0;             // f64 accumulation (proven R4/R5)
#pragma unroll
    for (int k = 0; k < K; ++k) {
        float hf = 1.0f / (1.0f + __expf(-e[k]));   // hardware v_exp_f32
        double h = (double)hf;
        m += (double)intervals[k] * h * sp;
        sp *= (1.0 - h);
    }
    mrl[row0 + tid] = (float)m;
}

__global__ void pair_kernel(const float* __restrict__ target,
                            const float* __restrict__ mrl,
                            double* __restrict__ pnum,
                            int* __restrict__ pcnt) {
    __shared__ __align__(16) float s_t[JSPAN];
    __shared__ __align__(16) float s_m[JSPAN];
    __shared__ double r_num[TPB];
    __shared__ int    r_cnt[TPB];

    const int tid = threadIdx.x;
    const int bid = blockIdx.x;
    const int ic  = bid >> 7;             // i-chunk (of 4096 rows)
    const int js  = bid & (NJ - 1);       // j-slice

    // each thread owns 4 i-rows at stride TPB (coalesced loads)
    float ti[IPT]; float mi[IPT]; bool ev[IPT];
#pragma unroll
    for (int k = 0; k < IPT; ++k) {
        const int i = ic * (TPB * IPT) + k * TPB + tid;
        const float2 tv = ((const float2*)target)[i];
        ti[k] = tv.x;
        ev[k] = (tv.y != 0.0f);
        mi[k] = mrl[i];
    }

    if (tid < JSPAN) {
        const int j = js * JSPAN + tid;
        s_t[tid] = ((const float2*)target)[j].x;
        s_m[tid] = mrl[j];
    }
    __syncthreads();

    const float4* s_t4 = (const float4*)s_t;
    const float4* s_m4 = (const float4*)s_m;

    float a[IPT][4];                      // fp32 chains (fully unrolled indices)
    int   c[IPT][4];
#pragma unroll
    for (int k = 0; k < IPT; ++k)
#pragma unroll
        for (int q = 0; q < 4; ++q) { a[k][q] = 0.0f; c[k][q] = 0; }

#pragma unroll
    for (int q = 0; q < JSPAN / 4; ++q) { // 16 iterations, 4 j each
        // broadcast ds_read_b128 (uniform address) -> conflict-free;
        // each read pair feeds 16 pair-updates (4 i-rows)
        const float4 tv = s_t4[q];
        const float4 mv = s_m4[q];
#pragma unroll
        for (int k = 0; k < IPT; ++k) {
            const bool b0 = ti[k] < tv.x, b1 = ti[k] < tv.y,
                       b2 = ti[k] < tv.z, b3 = ti[k] < tv.w;
            c[k][0] += b0; a[k][0] += b0 ? mv.x : 0.0f;
            c[k][1] += b1; a[k][1] += b1 ? mv.y : 0.0f;
            c[k][2] += b2; a[k][2] += b2 ? mv.z : 0.0f;
            c[k][3] += b3; a[k][3] += b3 ? mv.w : 0.0f;
        }
    }

    double num = 0.0;
    int    cnt = 0;
#pragma unroll
    for (int k = 0; k < IPT; ++k) {
        const int   ck = (c[k][0] + c[k][1]) + (c[k][2] + c[k][3]);
        const float ak = (a[k][0] + a[k][1]) + (a[k][2] + a[k][3]);  // <=64 terms
        if (ev[k]) {
            num += (double)ck * (double)mi[k] - (double)ak;
            cnt += ck;
        }
    }

    r_num[tid] = num;
    r_cnt[tid] = cnt;
    __syncthreads();
    for (int s = TPB / 2; s > 0; s >>= 1) {
        if (tid < s) {
            r_num[tid] += r_num[tid + s];
            r_cnt[tid] += r_cnt[tid + s];
        }
        __syncthreads();
    }
    if (tid == 0) {
        pnum[bid] = r_num[0];
        pcnt[bid] = r_cnt[0];
    }
}

__global__ void final_kernel(const double* __restrict__ pnum,
                             const int* __restrict__ pcnt,
                             float* __restrict__ out) {
    __shared__ double r_num[MTPB];
    __shared__ int    r_cnt[MTPB];
    const int tid = threadIdx.x;
    // NBLK == MTPB: one partial per thread, fixed order -> deterministic
    r_num[tid] = pnum[tid];
    r_cnt[tid] = pcnt[tid];
    __syncthreads();
    for (int s = MTPB / 2; s > 0; s >>= 1) {
        if (tid < s) {
            r_num[tid] += r_num[tid + s];
            r_cnt[tid] += r_cnt[tid + s];
        }
        __syncthreads();
    }
    if (tid == 0) out[0] = (float)(r_num[0] / (double)r_cnt[0]);
}

extern "C" void kernel_launch(void* const* d_in, const int* in_sizes, int n_in,
                              void* d_out, int out_size, void* d_ws, size_t ws_size,
                              hipStream_t stream) {
    const float* est       = (const float*)d_in[0];   // (N, K) fp32
    const float* target    = (const float*)d_in[1];   // (N, 2) fp32
    const float* intervals = (const float*)d_in[2];   // (K,)  fp32
    float* out = (float*)d_out;

    float*  mrl  = (float*)d_ws;
    double* pnum = (double*)((char*)d_ws + 32768);
    int*    pcnt = (int*)((char*)d_ws + 34816);

    mrl_kernel<<<N / MTPB, MTPB, 0, stream>>>(est, intervals, mrl);
    pair_kernel<<<NBLK, TPB, 0, stream>>>(target, mrl, pnum, pcnt);
    final_kernel<<<1, MTPB, 0, stream>>>(pnum, pcnt, out);
}